// Round 1
// baseline (3008.888 us; speedup 1.0000x reference)
//
#include <hip/hip_runtime.h>
#include <math.h>

#define WDIM 128
#define HDIM 128
#define BDIM 4
#define CDIM 256
#define NROI 2000
#define FIN  12544   // 256*49
#define FC   1024

typedef unsigned short bf16r;

__device__ __forceinline__ float bf2f(bf16r h) {
    return __uint_as_float(((unsigned)h) << 16);
}
__device__ __forceinline__ bf16r f2bf(float f) {
    unsigned u = __float_as_uint(f);
    u += 0x7FFFu + ((u >> 16) & 1u);   // round-to-nearest-even
    return (bf16r)(u >> 16);
}

// rois[n] -> batch idx + pooled-region geometry (matches reference round_half math)
__device__ __forceinline__ void roi_geom(const float* __restrict__ rois, int n,
                                         int& b, float& sw, float& sh,
                                         float& rw, float& rh) {
    const float* r = rois + (size_t)n * 5;
    b = (int)r[0];
    float r1 = floorf(r[1] + 0.5f);
    float r2 = floorf(r[2] + 0.5f);
    float r3 = floorf(r[3] + 0.5f);
    float r4 = floorf(r[4] + 0.5f);
    sw = r1 * 0.0625f - 0.5f;
    sh = r2 * 0.0625f - 0.5f;
    float ew = (r3 + 1.0f) * 0.0625f - 0.5f;
    float eh = (r4 + 1.0f) * 0.0625f - 0.5f;
    rw = fmaxf(ew - sw, 0.1f);
    rh = fmaxf(eh - sh, 0.1f);
}

// data [B,C,H,W] fp32 -> data_t [B,H,W,C] fp32 (channels-last for coalesced pooling)
__global__ __launch_bounds__(256) void transpose_kernel(const float* __restrict__ data,
                                                        float* __restrict__ data_t) {
    __shared__ float t[32][33];
    int x0 = blockIdx.x << 5;
    int c0 = blockIdx.y << 5;
    int b  = blockIdx.z >> 7;
    int y  = blockIdx.z & 127;
    int tx = threadIdx.x, ty = threadIdx.y;
#pragma unroll
    for (int i = 0; i < 32; i += 8)
        t[ty + i][tx] = data[(((size_t)b * CDIM + c0 + ty + i) * HDIM + y) * WDIM + x0 + tx];
    __syncthreads();
#pragma unroll
    for (int i = 0; i < 32; i += 8)
        data_t[(((size_t)b * HDIM + y) * WDIM + x0 + ty + i) * CDIM + c0 + tx] = t[tx][ty + i];
}

// Pass-1 pooling (offset = None). Writes xf bf16 in [n][po*256 + c] layout.
__global__ __launch_bounds__(256) void pool1_kernel(const float* __restrict__ data_t,
                                                    const float* __restrict__ rois,
                                                    bf16r* __restrict__ xf) {
    int n = blockIdx.y, po = blockIdx.x, c = threadIdx.x;
    int ph = po / 7, pw = po % 7;
    int b; float sw, sh, rw, rh;
    roi_geom(rois, n, b, sw, sh, rw, rh);
    float bw = rw / 7.0f, bh = rh / 7.0f;
    float subw = bw * 0.25f, subh = bh * 0.25f;
    float wstart = (float)pw * bw + sw;
    float hstart = (float)ph * bh + sh;
    const float* dp = data_t + (size_t)b * (HDIM * WDIM * CDIM) + c;
    float acc = 0.f, cnt = 0.f;
#pragma unroll
    for (int s = 0; s < 16; ++s) {
        float w = wstart + (float)(s & 3) * subw;
        float h = hstart + (float)(s >> 2) * subh;
        if (w >= -0.5f && w <= WDIM - 0.5f && h >= -0.5f && h <= HDIM - 0.5f) {
            float wc = fminf(fmaxf(w, 0.f), WDIM - 1.f);
            float hc = fminf(fmaxf(h, 0.f), HDIM - 1.f);
            int x0 = (int)floorf(wc), y0 = (int)floorf(hc);
            int x1 = min(x0 + 1, WDIM - 1), y1 = min(y0 + 1, HDIM - 1);
            float dx = wc - (float)x0, dy = hc - (float)y0;
            const float* p0 = dp + ((size_t)y0 * WDIM) * CDIM;
            const float* p1 = dp + ((size_t)y1 * WDIM) * CDIM;
            float v00 = p0[(size_t)x0 * CDIM];
            float v01 = p0[(size_t)x1 * CDIM];
            float v10 = p1[(size_t)x0 * CDIM];
            float v11 = p1[(size_t)x1 * CDIM];
            acc += (1.f - dx) * (1.f - dy) * v00 + dx * (1.f - dy) * v01
                 + (1.f - dx) * dy * v10 + dx * dy * v11;
            cnt += 1.f;
        }
    }
    float out = cnt > 0.f ? acc / cnt : 0.f;
    xf[(size_t)n * FIN + po * CDIM + c] = f2bf(out);
}

// Fused-column tiled fp32 GEMM: C = relu(A@B + bias). A bf16 [M,K], B fp32 [K,1024].
// Two virtual column halves (B0|B1) so GEMM1 does w1 and mw1 in one launch.
// permK: A's k index is po*256+c but weight rows are c*49+po -> remap row.
__global__ __launch_bounds__(256) void gemm_big_kernel(
        const bf16r* __restrict__ A, int M, int K,
        const float* __restrict__ B0, const float* __restrict__ bias0, bf16r* __restrict__ O0,
        const float* __restrict__ B1, const float* __restrict__ bias1, bf16r* __restrict__ O1,
        int permK) {
    const int Nper = 1024;
    __shared__ float As[16][68];    // [k][m], padded
    __shared__ float Bs[16][128];   // [k][n]
    int tid = threadIdx.x;
    int m0 = blockIdx.y * 64;
    int n0 = blockIdx.x * 128;
    const float* Bp; const float* biasp; bf16r* Op; int nc;
    if (n0 < Nper) { Bp = B0; biasp = bias0; Op = O0; nc = n0; }
    else           { Bp = B1; biasp = bias1; Op = O1; nc = n0 - Nper; }

    int tn = tid & 15, tm = tid >> 4;
    float acc[4][8];
#pragma unroll
    for (int i = 0; i < 4; ++i)
#pragma unroll
        for (int j = 0; j < 8; ++j) acc[i][j] = 0.f;

    int am = tid >> 2;           // 0..63   A tile row
    int ak = (tid & 3) << 2;     // 0,4,8,12 A tile k base
    int bkr = tid >> 4;          // 0..15   B tile k row
    int bn = (tid & 15) << 3;    // 0..120  B tile col base
    int gm = m0 + am;
    const bf16r* ap = A + (size_t)gm * K + ak;

    for (int k0 = 0; k0 < K; k0 += 16) {
        ushort4 a4 = make_ushort4(0, 0, 0, 0);
        if (gm < M) a4 = *(const ushort4*)(ap + k0);
        As[ak + 0][am] = bf2f(a4.x);
        As[ak + 1][am] = bf2f(a4.y);
        As[ak + 2][am] = bf2f(a4.z);
        As[ak + 3][am] = bf2f(a4.w);
        int gk = k0 + bkr;
        int row = permK ? ((gk & 255) * 49 + (gk >> 8)) : gk;
        const float* bp = Bp + (size_t)row * Nper + nc + bn;
        float4 bv0 = *(const float4*)bp;
        float4 bv1 = *(const float4*)(bp + 4);
        *(float4*)&Bs[bkr][bn]     = bv0;
        *(float4*)&Bs[bkr][bn + 4] = bv1;
        __syncthreads();
#pragma unroll
        for (int kk = 0; kk < 16; ++kk) {
            float4 af  = *(const float4*)&As[kk][tm << 2];
            float4 bf0 = *(const float4*)&Bs[kk][tn << 3];
            float4 bf1 = *(const float4*)&Bs[kk][(tn << 3) + 4];
            float a[4]  = {af.x, af.y, af.z, af.w};
            float bb[8] = {bf0.x, bf0.y, bf0.z, bf0.w, bf1.x, bf1.y, bf1.z, bf1.w};
#pragma unroll
            for (int i = 0; i < 4; ++i)
#pragma unroll
                for (int j = 0; j < 8; ++j)
                    acc[i][j] = fmaf(a[i], bb[j], acc[i][j]);
        }
        __syncthreads();
    }
#pragma unroll
    for (int i = 0; i < 4; ++i) {
        int gmm = m0 + (tm << 2) + i;
        if (gmm < M) {
#pragma unroll
            for (int j = 0; j < 8; ++j) {
                float v = acc[i][j] + biasp[nc + (tn << 3) + j];
                v = fmaxf(v, 0.f);
                Op[(size_t)gmm * 1024 + nc + (tn << 3) + j] = f2bf(v);
            }
        }
    }
}

// Small-N GEMM (N=98 offset head, N=49 mask head). 4 rows per block, K=1024.
// act: 0=none, 2=sigmoid
__global__ __launch_bounds__(128) void gemm_small_kernel(
        const bf16r* __restrict__ A, const float* __restrict__ B,
        const float* __restrict__ bias, float* __restrict__ O, int N, int act) {
    __shared__ float a_sh[4][1024];
    int m0 = blockIdx.x * 4;
    for (int i = threadIdx.x; i < 4096; i += 128) {
        int r = i >> 10, k = i & 1023;
        a_sh[r][k] = bf2f(A[(size_t)(m0 + r) * 1024 + k]);
    }
    __syncthreads();
    int j = threadIdx.x;
    if (j < N) {
        float acc0 = 0.f, acc1 = 0.f, acc2 = 0.f, acc3 = 0.f;
#pragma unroll 8
        for (int k = 0; k < 1024; ++k) {
            float bv = B[(size_t)k * N + j];
            acc0 = fmaf(a_sh[0][k], bv, acc0);
            acc1 = fmaf(a_sh[1][k], bv, acc1);
            acc2 = fmaf(a_sh[2][k], bv, acc2);
            acc3 = fmaf(a_sh[3][k], bv, acc3);
        }
        float bb = bias[j];
        float v[4] = {acc0 + bb, acc1 + bb, acc2 + bb, acc3 + bb};
#pragma unroll
        for (int r = 0; r < 4; ++r) {
            float x = v[r];
            if (act == 2) x = 1.f / (1.f + expf(-x));
            O[(size_t)(m0 + r) * N + j] = x;
        }
    }
}

// Pass-2 pooling with offsets, times mask; LDS re-layout so the final
// [n][c*49+po] store is one contiguous coalesced 50KB write per roi.
__global__ __launch_bounds__(256) void pool2_kernel(const float* __restrict__ data_t,
                                                    const float* __restrict__ rois,
                                                    const float* __restrict__ offs,
                                                    const float* __restrict__ mask,
                                                    float* __restrict__ out) {
    __shared__ float tile[FIN];   // 49*256 floats = 50,176 B
    int n = blockIdx.x, c = threadIdx.x;
    int b; float sw, sh, rw, rh;
    roi_geom(rois, n, b, sw, sh, rw, rh);
    float bw = rw / 7.0f, bh = rh / 7.0f;
    float subw = bw * 0.25f, subh = bh * 0.25f;
    const float* dp = data_t + (size_t)b * (HDIM * WDIM * CDIM) + c;
    for (int po = 0; po < 49; ++po) {
        int ph = po / 7, pw = po % 7;
        float ow = offs[(size_t)n * 98 + po];
        float oh = offs[(size_t)n * 98 + 49 + po];
        float wstart = (float)pw * bw + sw + ow * 0.1f * rw;
        float hstart = (float)ph * bh + sh + oh * 0.1f * rh;
        float acc = 0.f, cnt = 0.f;
#pragma unroll
        for (int s = 0; s < 16; ++s) {
            float w = wstart + (float)(s & 3) * subw;
            float h = hstart + (float)(s >> 2) * subh;
            if (w >= -0.5f && w <= WDIM - 0.5f && h >= -0.5f && h <= HDIM - 0.5f) {
                float wc = fminf(fmaxf(w, 0.f), WDIM - 1.f);
                float hc = fminf(fmaxf(h, 0.f), HDIM - 1.f);
                int x0 = (int)floorf(wc), y0 = (int)floorf(hc);
                int x1 = min(x0 + 1, WDIM - 1), y1 = min(y0 + 1, HDIM - 1);
                float dx = wc - (float)x0, dy = hc - (float)y0;
                const float* p0 = dp + ((size_t)y0 * WDIM) * CDIM;
                const float* p1 = dp + ((size_t)y1 * WDIM) * CDIM;
                float v00 = p0[(size_t)x0 * CDIM];
                float v01 = p0[(size_t)x1 * CDIM];
                float v10 = p1[(size_t)x0 * CDIM];
                float v11 = p1[(size_t)x1 * CDIM];
                acc += (1.f - dx) * (1.f - dy) * v00 + dx * (1.f - dy) * v01
                     + (1.f - dx) * dy * v10 + dx * dy * v11;
                cnt += 1.f;
            }
        }
        float v = cnt > 0.f ? acc / cnt : 0.f;
        tile[c * 49 + po] = v * mask[(size_t)n * 49 + po];
    }
    __syncthreads();
    float* op = out + (size_t)n * FIN;
    for (int i = threadIdx.x; i < FIN; i += 256) op[i] = tile[i];
}

extern "C" void kernel_launch(void* const* d_in, const int* in_sizes, int n_in,
                              void* d_out, int out_size, void* d_ws, size_t ws_size,
                              hipStream_t stream) {
    const float* data = (const float*)d_in[0];
    const float* rois = (const float*)d_in[1];
    const float* w1   = (const float*)d_in[2];
    const float* b1   = (const float*)d_in[3];
    const float* w2   = (const float*)d_in[4];
    const float* b2   = (const float*)d_in[5];
    const float* w3   = (const float*)d_in[6];
    const float* b3   = (const float*)d_in[7];
    const float* mw1  = (const float*)d_in[8];
    const float* mb1  = (const float*)d_in[9];
    const float* mw2  = (const float*)d_in[10];
    const float* mb2  = (const float*)d_in[11];
    float* out = (float*)d_out;

    char* w = (char*)d_ws;
    float* data_t = (float*)w;  w += (size_t)BDIM * HDIM * WDIM * CDIM * 4;  // 67.1 MB
    bf16r* xf     = (bf16r*)w;  w += (size_t)NROI * FIN * 2;                 // 50.2 MB
    bf16r* h1     = (bf16r*)w;  w += (size_t)NROI * FC * 2;
    bf16r* m1     = (bf16r*)w;  w += (size_t)NROI * FC * 2;
    bf16r* h2     = (bf16r*)w;  w += (size_t)NROI * FC * 2;
    float* offs   = (float*)w;  w += (size_t)NROI * 98 * 4;
    float* maskb  = (float*)w;  w += (size_t)NROI * 49 * 4;

    transpose_kernel<<<dim3(4, 8, 512), dim3(32, 8), 0, stream>>>(data, data_t);
    pool1_kernel<<<dim3(49, NROI), 256, 0, stream>>>(data_t, rois, xf);
    // fused xf@w1 and xf@mw1 (relu) -> h1, m1
    gemm_big_kernel<<<dim3(16, 32), 256, 0, stream>>>(xf, NROI, FIN,
                                                      w1, b1, h1, mw1, mb1, m1, 1);
    // h1@w2 (relu) -> h2
    gemm_big_kernel<<<dim3(8, 32), 256, 0, stream>>>(h1, NROI, FC,
                                                     w2, b2, h2, nullptr, nullptr, nullptr, 0);
    gemm_small_kernel<<<dim3(500), 128, 0, stream>>>(h2, w3, b3, offs, 98, 0);
    gemm_small_kernel<<<dim3(500), 128, 0, stream>>>(m1, mw2, mb2, maskb, 49, 2);
    pool2_kernel<<<dim3(NROI), 256, 0, stream>>>(data_t, rois, offs, maskb, out);
}

// Round 2
// 1683.518 us; speedup vs baseline: 1.7873x; 1.7873x over previous
//
#include <hip/hip_runtime.h>
#include <math.h>

#define WDIM 128
#define HDIM 128
#define BDIM 4
#define CDIM 256
#define NROI 2000
#define MPAD 2048
#define FIN  12544   // 256*49
#define FC   1024

typedef unsigned short bf16r;
typedef __attribute__((ext_vector_type(8))) short bf16x8;   // 8 bf16 = 4 VGPRs
typedef __attribute__((ext_vector_type(4))) float f32x4;

__device__ __forceinline__ float bf2f(bf16r h) {
    return __uint_as_float(((unsigned)h) << 16);
}
__device__ __forceinline__ bf16r f2bf(float f) {
    unsigned u = __float_as_uint(f);
    u += 0x7FFFu + ((u >> 16) & 1u);
    return (bf16r)(u >> 16);
}

__device__ __forceinline__ void async16(const bf16r* g, bf16r* l) {
    __builtin_amdgcn_global_load_lds(
        (const __attribute__((address_space(1))) unsigned int*)g,
        (__attribute__((address_space(3))) unsigned int*)l, 16, 0, 0);
}

__device__ __forceinline__ void roi_geom(const float* __restrict__ rois, int n,
                                         int& b, float& sw, float& sh,
                                         float& rw, float& rh) {
    const float* r = rois + (size_t)n * 5;
    b = (int)r[0];
    float r1 = floorf(r[1] + 0.5f);
    float r2 = floorf(r[2] + 0.5f);
    float r3 = floorf(r[3] + 0.5f);
    float r4 = floorf(r[4] + 0.5f);
    sw = r1 * 0.0625f - 0.5f;
    sh = r2 * 0.0625f - 0.5f;
    float ew = (r3 + 1.0f) * 0.0625f - 0.5f;
    float eh = (r4 + 1.0f) * 0.0625f - 0.5f;
    rw = fmaxf(ew - sw, 0.1f);
    rh = fmaxf(eh - sh, 0.1f);
}

// data [B,C,H,W] -> data_t [B,H,W,C]
__global__ __launch_bounds__(256) void transpose_kernel(const float* __restrict__ data,
                                                        float* __restrict__ data_t) {
    __shared__ float t[32][33];
    int x0 = blockIdx.x << 5;
    int c0 = blockIdx.y << 5;
    int b  = blockIdx.z >> 7;
    int y  = blockIdx.z & 127;
    int tx = threadIdx.x, ty = threadIdx.y;
#pragma unroll
    for (int i = 0; i < 32; i += 8)
        t[ty + i][tx] = data[(((size_t)b * CDIM + c0 + ty + i) * HDIM + y) * WDIM + x0 + tx];
    __syncthreads();
#pragma unroll
    for (int i = 0; i < 32; i += 8)
        data_t[(((size_t)b * HDIM + y) * WDIM + x0 + ty + i) * CDIM + c0 + tx] = t[tx][ty + i];
}

// fp32 weights -> bf16, transposed to Bt[n][k] (k contiguous), optional k-perm.
// Bt[n][k] = src[(perm? (k&255)*49+(k>>8) : k)][col], col = n or n-nsplit (srcB).
__global__ __launch_bounds__(256) void conv_kernel(const float* __restrict__ srcA,
                                                   const float* __restrict__ srcB,
                                                   int nsplit, int ncols, int Nout,
                                                   int K, int perm,
                                                   bf16r* __restrict__ dst) {
    __shared__ float t[32][33];
    int k0 = blockIdx.x << 5, n0 = blockIdx.y << 5;
    int tx = threadIdx.x & 31, ty = threadIdx.x >> 5;
#pragma unroll
    for (int i = 0; i < 32; i += 8) {
        int k = k0 + ty + i;
        int n = n0 + tx;
        const float* s = (n < nsplit) ? srcA : srcB;
        int col = (n < nsplit) ? n : n - nsplit;
        int row = perm ? ((k & 255) * 49 + (k >> 8)) : k;
        float v = (n < Nout && col < ncols) ? s[(size_t)row * ncols + col] : 0.f;
        t[ty + i][tx] = v;
    }
    __syncthreads();
#pragma unroll
    for (int i = 0; i < 32; i += 8) {
        int n = n0 + ty + i;
        if (n < Nout) dst[(size_t)n * K + k0 + tx] = f2bf(t[tx][ty + i]);
    }
}

// Pass-1 pooling (offset = None). xf bf16 [n][po*256 + c].
__global__ __launch_bounds__(256) void pool1_kernel(const float* __restrict__ data_t,
                                                    const float* __restrict__ rois,
                                                    bf16r* __restrict__ xf) {
    int n = blockIdx.y, po = blockIdx.x, c = threadIdx.x;
    int ph = po / 7, pw = po % 7;
    int b; float sw, sh, rw, rh;
    roi_geom(rois, n, b, sw, sh, rw, rh);
    float bw = rw / 7.0f, bh = rh / 7.0f;
    float subw = bw * 0.25f, subh = bh * 0.25f;
    float wstart = (float)pw * bw + sw;
    float hstart = (float)ph * bh + sh;
    const float* dp = data_t + (size_t)b * (HDIM * WDIM * CDIM) + c;
    float acc = 0.f, cnt = 0.f;
#pragma unroll
    for (int s = 0; s < 16; ++s) {
        float w = wstart + (float)(s & 3) * subw;
        float h = hstart + (float)(s >> 2) * subh;
        if (w >= -0.5f && w <= WDIM - 0.5f && h >= -0.5f && h <= HDIM - 0.5f) {
            float wc = fminf(fmaxf(w, 0.f), WDIM - 1.f);
            float hc = fminf(fmaxf(h, 0.f), HDIM - 1.f);
            int x0 = (int)floorf(wc), y0 = (int)floorf(hc);
            int x1 = min(x0 + 1, WDIM - 1), y1 = min(y0 + 1, HDIM - 1);
            float dx = wc - (float)x0, dy = hc - (float)y0;
            const float* p0 = dp + ((size_t)y0 * WDIM) * CDIM;
            const float* p1 = dp + ((size_t)y1 * WDIM) * CDIM;
            float v00 = p0[(size_t)x0 * CDIM];
            float v01 = p0[(size_t)x1 * CDIM];
            float v10 = p1[(size_t)x0 * CDIM];
            float v11 = p1[(size_t)x1 * CDIM];
            acc += (1.f - dx) * (1.f - dy) * v00 + dx * (1.f - dy) * v01
                 + (1.f - dx) * dy * v10 + dx * dy * v11;
            cnt += 1.f;
        }
    }
    float out = cnt > 0.f ? acc / cnt : 0.f;
    xf[(size_t)n * FIN + po * CDIM + c] = f2bf(out);
}

// MFMA bf16 GEMM: P[z] = A[M,K] @ Bt[N,K]^T  (fp32 partials, split-K).
// 128x128 tile, BK=32, 4 waves (each 64x64), XOR-swizzled LDS chunks.
__global__ __launch_bounds__(256) void gemm_mfma_kernel(
        const bf16r* __restrict__ A, int lda,
        const bf16r* __restrict__ Bt, int K,
        float* __restrict__ P, int Npad, int KS) {
    __shared__ bf16r As[128 * 32];
    __shared__ bf16r Bs[128 * 32];
    int tid = threadIdx.x;
    int wave = tid >> 6, lane = tid & 63;
    int m0 = blockIdx.y << 7, n0 = blockIdx.x << 7;
    int z = blockIdx.z;

    // staging: lane i covers row wave*32 + j*16 + (i>>2), physical chunk i&3.
    // logical k-chunk = phys ^ ((row>>1)&3)  (row bits 1-2 = (i>>3)&3)
    int srow = lane >> 2;
    int kchunk = ((lane & 3) ^ ((lane >> 3) & 3)) << 3;
    const bf16r* aG0 = A + (size_t)(m0 + wave * 32 + srow) * lda + kchunk;
    const bf16r* aG1 = A + (size_t)(m0 + wave * 32 + 16 + srow) * lda + kchunk;
    const bf16r* bG0 = Bt + (size_t)(n0 + wave * 32 + srow) * K + kchunk;
    const bf16r* bG1 = Bt + (size_t)(n0 + wave * 32 + 16 + srow) * K + kchunk;
    bf16r* aL0 = As + wave * 1024;
    bf16r* aL1 = As + wave * 1024 + 512;
    bf16r* bL0 = Bs + wave * 1024;
    bf16r* bL1 = Bs + wave * 1024 + 512;

    int l15 = lane & 15, quad = lane >> 4;
    int wr = wave >> 1, wc = wave & 1;
    int psw = (quad ^ ((l15 >> 1) & 3)) << 3;   // physical chunk (elems)
    int aoff[4], boff[4];
#pragma unroll
    for (int t = 0; t < 4; ++t) {
        aoff[t] = ((wr * 64 + t * 16 + l15) * 32 + psw) * 2;   // bytes
        boff[t] = ((wc * 64 + t * 16 + l15) * 32 + psw) * 2;
    }

    f32x4 acc[4][4];
#pragma unroll
    for (int i = 0; i < 4; ++i)
#pragma unroll
        for (int j = 0; j < 4; ++j) acc[i][j] = (f32x4){0.f, 0.f, 0.f, 0.f};

    int iters = K >> 5;
    int i0 = (int)((long)iters * z / KS);
    int i1 = (int)((long)iters * (z + 1) / KS);

    {
        size_t k0 = (size_t)i0 << 5;
        async16(aG0 + k0, aL0); async16(aG1 + k0, aL1);
        async16(bG0 + k0, bL0); async16(bG1 + k0, bL1);
    }
    for (int it = i0; it < i1; ++it) {
        __syncthreads();   // staging complete (compiler drains vmcnt before barrier)
        bf16x8 af[4], bfv[4];
#pragma unroll
        for (int t = 0; t < 4; ++t) af[t] = *(const bf16x8*)((const char*)As + aoff[t]);
#pragma unroll
        for (int t = 0; t < 4; ++t) bfv[t] = *(const bf16x8*)((const char*)Bs + boff[t]);
        __syncthreads();   // all waves consumed LDS
        if (it + 1 < i1) { // stage next tile; overlaps with MFMA below
            size_t k0 = (size_t)(it + 1) << 5;
            async16(aG0 + k0, aL0); async16(aG1 + k0, aL1);
            async16(bG0 + k0, bL0); async16(bG1 + k0, bL1);
        }
#pragma unroll
        for (int i = 0; i < 4; ++i)
#pragma unroll
            for (int j = 0; j < 4; ++j)
                acc[i][j] = __builtin_amdgcn_mfma_f32_16x16x32_bf16(af[i], bfv[j], acc[i][j], 0, 0, 0);
    }

    float* Pp = P + (size_t)z * MPAD * Npad;
#pragma unroll
    for (int i = 0; i < 4; ++i) {
        int row = m0 + wr * 64 + i * 16 + quad * 4;
#pragma unroll
        for (int j = 0; j < 4; ++j) {
            int col = n0 + wc * 64 + j * 16 + l15;
            float* o = Pp + (size_t)row * Npad + col;
#pragma unroll
            for (int r = 0; r < 4; ++r) o[(size_t)r * Npad] = acc[i][j][r];
        }
    }
}

// sum split-K partials + bias + activation + dtype convert
// outmode: 0 = relu->bf16, 1 = none->f32, 2 = sigmoid->f32
__global__ __launch_bounds__(256) void reduce_kernel(
        const float* __restrict__ P, int shift, int KS,
        const float* __restrict__ bias0, const float* __restrict__ bias1, int bsplit,
        void* __restrict__ Out, int ldo, int M, int Nreal, int outmode) {
    int idx = blockIdx.x * 256 + threadIdx.x;
    int Npad = 1 << shift;
    int row = idx >> shift, col = idx & (Npad - 1);
    float s = 0.f;
    size_t plane = (size_t)MPAD << shift;
    for (int zz = 0; zz < KS; ++zz) s += P[(size_t)zz * plane + idx];
    if (row < M && col < Nreal) {
        float b = (col < bsplit) ? bias0[col] : bias1[col - bsplit];
        float v = s + b;
        if (outmode == 0) {
            v = fmaxf(v, 0.f);
            ((bf16r*)Out)[(size_t)row * ldo + col] = f2bf(v);
        } else {
            if (outmode == 2) v = 1.f / (1.f + expf(-v));
            ((float*)Out)[(size_t)row * ldo + col] = v;
        }
    }
}

// Pass-2 pooling with offsets, times mask.
__global__ __launch_bounds__(256) void pool2_kernel(const float* __restrict__ data_t,
                                                    const float* __restrict__ rois,
                                                    const float* __restrict__ offs,
                                                    const float* __restrict__ mask,
                                                    float* __restrict__ out) {
    __shared__ float tile[FIN];
    int n = blockIdx.x, c = threadIdx.x;
    int b; float sw, sh, rw, rh;
    roi_geom(rois, n, b, sw, sh, rw, rh);
    float bw = rw / 7.0f, bh = rh / 7.0f;
    float subw = bw * 0.25f, subh = bh * 0.25f;
    const float* dp = data_t + (size_t)b * (HDIM * WDIM * CDIM) + c;
    for (int po = 0; po < 49; ++po) {
        int ph = po / 7, pw = po % 7;
        float ow = offs[(size_t)n * 98 + po];
        float oh = offs[(size_t)n * 98 + 49 + po];
        float wstart = (float)pw * bw + sw + ow * 0.1f * rw;
        float hstart = (float)ph * bh + sh + oh * 0.1f * rh;
        float acc = 0.f, cnt = 0.f;
#pragma unroll
        for (int s = 0; s < 16; ++s) {
            float w = wstart + (float)(s & 3) * subw;
            float h = hstart + (float)(s >> 2) * subh;
            if (w >= -0.5f && w <= WDIM - 0.5f && h >= -0.5f && h <= HDIM - 0.5f) {
                float wc = fminf(fmaxf(w, 0.f), WDIM - 1.f);
                float hc = fminf(fmaxf(h, 0.f), HDIM - 1.f);
                int x0 = (int)floorf(wc), y0 = (int)floorf(hc);
                int x1 = min(x0 + 1, WDIM - 1), y1 = min(y0 + 1, HDIM - 1);
                float dx = wc - (float)x0, dy = hc - (float)y0;
                const float* p0 = dp + ((size_t)y0 * WDIM) * CDIM;
                const float* p1 = dp + ((size_t)y1 * WDIM) * CDIM;
                float v00 = p0[(size_t)x0 * CDIM];
                float v01 = p0[(size_t)x1 * CDIM];
                float v10 = p1[(size_t)x0 * CDIM];
                float v11 = p1[(size_t)x1 * CDIM];
                acc += (1.f - dx) * (1.f - dy) * v00 + dx * (1.f - dy) * v01
                     + (1.f - dx) * dy * v10 + dx * dy * v11;
                cnt += 1.f;
            }
        }
        float v = cnt > 0.f ? acc / cnt : 0.f;
        tile[c * 49 + po] = v * mask[(size_t)n * 49 + po];
    }
    __syncthreads();
    float* op = out + (size_t)n * FIN;
    for (int i = threadIdx.x; i < FIN; i += 256) op[i] = tile[i];
}

extern "C" void kernel_launch(void* const* d_in, const int* in_sizes, int n_in,
                              void* d_out, int out_size, void* d_ws, size_t ws_size,
                              hipStream_t stream) {
    const float* data = (const float*)d_in[0];
    const float* rois = (const float*)d_in[1];
    const float* w1   = (const float*)d_in[2];
    const float* b1   = (const float*)d_in[3];
    const float* w2   = (const float*)d_in[4];
    const float* b2   = (const float*)d_in[5];
    const float* w3   = (const float*)d_in[6];
    const float* b3   = (const float*)d_in[7];
    const float* mw1  = (const float*)d_in[8];
    const float* mb1  = (const float*)d_in[9];
    const float* mw2  = (const float*)d_in[10];
    const float* mb2  = (const float*)d_in[11];
    float* out = (float*)d_out;

    char* w = (char*)d_ws;
    size_t off = 0;
    auto carve = [&](size_t bytes) {
        void* p = w + off;
        off += (bytes + 255) & ~(size_t)255;
        return p;
    };
    float* data_t = (float*)carve((size_t)BDIM * HDIM * WDIM * CDIM * 4);   // 67.1 MB
    bf16r* xf     = (bf16r*)carve((size_t)MPAD * FIN * 2);                  // 51.4 MB
    bf16r* bt1    = (bf16r*)carve((size_t)MPAD * FIN * 2);                  // 51.4 MB
    bf16r* hm     = (bf16r*)carve((size_t)MPAD * 2048 * 2);                 // 8.4 MB
    bf16r* h2     = (bf16r*)carve((size_t)MPAD * 1024 * 2);                 // 4.2 MB
    bf16r* bt2    = (bf16r*)carve((size_t)1024 * 1024 * 2);
    bf16r* bt3    = (bf16r*)carve((size_t)128 * 1024 * 2);
    bf16r* bt4    = (bf16r*)carve((size_t)128 * 1024 * 2);
    float* offs   = (float*)carve((size_t)NROI * 98 * 4);
    float* maskb  = (float*)carve((size_t)NROI * 49 * 4);
    float* P      = (float*)carve((size_t)3 * MPAD * 2048 * 4);             // 50.3 MB

    // weight conversion (transposed bf16; bt1 fuses w1|mw1 with k-perm)
    conv_kernel<<<dim3(392, 64), 256, 0, stream>>>(w1, mw1, 1024, 1024, 2048, FIN, 1, bt1);
    conv_kernel<<<dim3(32, 32), 256, 0, stream>>>(w2, w2, 1 << 30, 1024, 1024, 1024, 0, bt2);
    conv_kernel<<<dim3(32, 4), 256, 0, stream>>>(w3, w3, 1 << 30, 98, 98, 1024, 0, bt3);
    conv_kernel<<<dim3(32, 2), 256, 0, stream>>>(mw2, mw2, 1 << 30, 49, 49, 1024, 0, bt4);
    transpose_kernel<<<dim3(4, 8, 512), dim3(32, 8), 0, stream>>>(data, data_t);
    pool1_kernel<<<dim3(49, NROI), 256, 0, stream>>>(data_t, rois, xf);

    // GEMM1: xf @ [w1|mw1] -> hm (relu bf16, fused bias split)
    gemm_mfma_kernel<<<dim3(16, 16, 3), 256, 0, stream>>>(xf, FIN, bt1, FIN, P, 2048, 3);
    reduce_kernel<<<16384, 256, 0, stream>>>(P, 11, 3, b1, mb1, 1024, hm, 2048, NROI, 2048, 0);
    // GEMM2: h1 @ w2 -> h2 (relu bf16)
    gemm_mfma_kernel<<<dim3(8, 16, 4), 256, 0, stream>>>(hm, 2048, bt2, 1024, P, 1024, 4);
    reduce_kernel<<<8192, 256, 0, stream>>>(P, 10, 4, b2, b2, 1 << 30, h2, 1024, NROI, 1024, 0);
    // offset head: h2 @ w3 -> offs (fp32)
    gemm_mfma_kernel<<<dim3(1, 16, 8), 256, 0, stream>>>(h2, 1024, bt3, 1024, P, 128, 8);
    reduce_kernel<<<1024, 256, 0, stream>>>(P, 7, 8, b3, b3, 1 << 30, offs, 98, NROI, 98, 1);
    // mask head: m1 @ mw2 -> maskb (sigmoid fp32)
    gemm_mfma_kernel<<<dim3(1, 16, 8), 256, 0, stream>>>(hm + 1024, 2048, bt4, 1024, P, 128, 8);
    reduce_kernel<<<1024, 256, 0, stream>>>(P, 7, 8, mb2, mb2, 1 << 30, maskb, 49, NROI, 49, 2);

    pool2_kernel<<<dim3(NROI), 256, 0, stream>>>(data_t, rois, offs, maskb, out);
}

// Round 3
// 946.842 us; speedup vs baseline: 3.1778x; 1.7780x over previous
//
#include <hip/hip_runtime.h>
#include <math.h>

#define WDIM 128
#define HDIM 128
#define BDIM 4
#define CDIM 256
#define NROI 2000
#define MPAD 2048
#define FIN  12544   // 256*49
#define FC   1024

typedef unsigned short bf16r;
typedef __attribute__((ext_vector_type(8))) short bf16x8;   // 8 bf16 = 4 VGPRs
typedef __attribute__((ext_vector_type(4))) float f32x4;

__device__ __forceinline__ float bf2f(bf16r h) {
    return __uint_as_float(((unsigned)h) << 16);
}
__device__ __forceinline__ bf16r f2bf(float f) {
    unsigned u = __float_as_uint(f);
    u += 0x7FFFu + ((u >> 16) & 1u);
    return (bf16r)(u >> 16);
}

__device__ __forceinline__ void async16(const bf16r* g, bf16r* l) {
    __builtin_amdgcn_global_load_lds(
        (const __attribute__((address_space(1))) unsigned int*)g,
        (__attribute__((address_space(3))) unsigned int*)l, 16, 0, 0);
}

__device__ __forceinline__ void roi_geom(const float* __restrict__ rois, int n,
                                         int& b, float& sw, float& sh,
                                         float& rw, float& rh) {
    const float* r = rois + (size_t)n * 5;
    b = (int)r[0];
    float r1 = floorf(r[1] + 0.5f);
    float r2 = floorf(r[2] + 0.5f);
    float r3 = floorf(r[3] + 0.5f);
    float r4 = floorf(r[4] + 0.5f);
    sw = r1 * 0.0625f - 0.5f;
    sh = r2 * 0.0625f - 0.5f;
    float ew = (r3 + 1.0f) * 0.0625f - 0.5f;
    float eh = (r4 + 1.0f) * 0.0625f - 0.5f;
    rw = fmaxf(ew - sw, 0.1f);
    rh = fmaxf(eh - sh, 0.1f);
}

// build one sample descriptor. Returns packed desc + dx/dy.
// desc: bits[0:22] = element offset (y0*128+x0)*256; bit29 = x-step valid;
//       bit30 = y-step valid; bit31 = sample valid.
__device__ __forceinline__ unsigned sample_desc(float w, float h, float2& xy) {
    bool valid = (w >= -0.5f) & (w <= 127.5f) & (h >= -0.5f) & (h <= 127.5f);
    float wc = fminf(fmaxf(w, 0.f), 127.f);
    float hc = fminf(fmaxf(h, 0.f), 127.f);
    int x0 = (int)floorf(wc), y0 = (int)floorf(hc);
    unsigned d = (unsigned)((y0 << 15) | (x0 << 8));
    if (x0 < 127) d |= 1u << 29;
    if (y0 < 127) d |= 1u << 30;
    if (valid) d |= 1u << 31;
    xy = make_float2(wc - (float)x0, hc - (float)y0);
    return d;
}

// data [B,C,H,W] -> data_t [B,H,W,C]
__global__ __launch_bounds__(256) void transpose_kernel(const float* __restrict__ data,
                                                        float* __restrict__ data_t) {
    __shared__ float t[32][33];
    int x0 = blockIdx.x << 5;
    int c0 = blockIdx.y << 5;
    int b  = blockIdx.z >> 7;
    int y  = blockIdx.z & 127;
    int tx = threadIdx.x, ty = threadIdx.y;
#pragma unroll
    for (int i = 0; i < 32; i += 8)
        t[ty + i][tx] = data[(((size_t)b * CDIM + c0 + ty + i) * HDIM + y) * WDIM + x0 + tx];
    __syncthreads();
#pragma unroll
    for (int i = 0; i < 32; i += 8)
        data_t[(((size_t)b * HDIM + y) * WDIM + x0 + ty + i) * CDIM + c0 + tx] = t[tx][ty + i];
}

// fp32 weights -> bf16, transposed to Bt[n][k] (k contiguous), optional k-perm.
__global__ __launch_bounds__(256) void conv_kernel(const float* __restrict__ srcA,
                                                   const float* __restrict__ srcB,
                                                   int nsplit, int ncols, int Nout,
                                                   int K, int perm,
                                                   bf16r* __restrict__ dst) {
    __shared__ float t[32][33];
    int k0 = blockIdx.x << 5, n0 = blockIdx.y << 5;
    int tx = threadIdx.x & 31, ty = threadIdx.x >> 5;
#pragma unroll
    for (int i = 0; i < 32; i += 8) {
        int k = k0 + ty + i;
        int n = n0 + tx;
        const float* s = (n < nsplit) ? srcA : srcB;
        int col = (n < nsplit) ? n : n - nsplit;
        int row = perm ? ((k & 255) * 49 + (k >> 8)) : k;
        float v = (n < Nout && col < ncols) ? s[(size_t)row * ncols + col] : 0.f;
        t[ty + i][tx] = v;
    }
    __syncthreads();
#pragma unroll
    for (int i = 0; i < 32; i += 8) {
        int n = n0 + ty + i;
        if (n < Nout) dst[(size_t)n * K + k0 + tx] = f2bf(t[tx][ty + i]);
    }
}

// Pass-1 pooling (offset = None). xf bf16 [n][po*256 + c].
// One roi per block; phase1 builds 784 sample descriptors in LDS (geometry
// amortized over channels); phase2: lane = 4 channels (float4), wave = po slot.
__global__ __launch_bounds__(512) void pool1_kernel(const float* __restrict__ data_t,
                                                    const float* __restrict__ rois,
                                                    bf16r* __restrict__ xf) {
    __shared__ unsigned desc[784];
    __shared__ float2 dxy[784];
    __shared__ float scale[49];
    int n = blockIdx.x, tid = threadIdx.x;
    int b; float sw, sh, rw, rh;
    roi_geom(rois, n, b, sw, sh, rw, rh);
    float bw = rw / 7.0f, bh = rh / 7.0f;
    float subw = bw * 0.25f, subh = bh * 0.25f;
    if (tid < 49) scale[tid] = 0.f;
    __syncthreads();
    for (int idx = tid; idx < 784; idx += 512) {
        int po = idx >> 4, s = idx & 15;
        int ph = po / 7, pw = po - ph * 7;
        float w = (float)pw * bw + sw + (float)(s & 3) * subw;
        float h = (float)ph * bh + sh + (float)(s >> 2) * subh;
        float2 xy;
        unsigned d = sample_desc(w, h, xy);
        desc[idx] = d;
        dxy[idx] = xy;
        if ((int)d < 0) atomicAdd(&scale[po], 1.f);
    }
    __syncthreads();
    if (tid < 49) { float c = scale[tid]; scale[tid] = c > 0.f ? 1.f / c : 0.f; }
    __syncthreads();
    int wave = tid >> 6, lane = tid & 63, c4 = lane << 2;
    const float* dpb = data_t + (size_t)b * (HDIM * WDIM * CDIM) + c4;
    for (int po = wave; po < 49; po += 8) {
        float4 acc = make_float4(0.f, 0.f, 0.f, 0.f);
#pragma unroll 4
        for (int s = 0; s < 16; ++s) {
            unsigned d = desc[po * 16 + s];
            if ((int)d < 0) {   // wave-uniform branch
                float2 xy = dxy[po * 16 + s];
                int off = d & 0x3FFFFF;
                int xo = (d >> 21) & 0x100;
                int yo = (d >> 15) & 0x8000;
                const float* p = dpb + off;
                float4 v00 = *(const float4*)(p);
                float4 v01 = *(const float4*)(p + xo);
                float4 v10 = *(const float4*)(p + yo);
                float4 v11 = *(const float4*)(p + xo + yo);
                float ax = 1.f - xy.x, ay = 1.f - xy.y;
                float w00 = ax * ay, w01 = xy.x * ay, w10 = ax * xy.y, w11 = xy.x * xy.y;
                acc.x += w00 * v00.x + w01 * v01.x + w10 * v10.x + w11 * v11.x;
                acc.y += w00 * v00.y + w01 * v01.y + w10 * v10.y + w11 * v11.y;
                acc.z += w00 * v00.z + w01 * v01.z + w10 * v10.z + w11 * v11.z;
                acc.w += w00 * v00.w + w01 * v01.w + w10 * v10.w + w11 * v11.w;
            }
        }
        float sc = scale[po];
        ushort4 o;
        o.x = f2bf(acc.x * sc); o.y = f2bf(acc.y * sc);
        o.z = f2bf(acc.z * sc); o.w = f2bf(acc.w * sc);
        *(ushort4*)(xf + (size_t)n * FIN + po * 256 + c4) = o;
    }
}

// Pass-2 pooling with offsets, times mask. Same structure as pool1 plus a
// XOR-swizzled 49x256 LDS out-tile so the [c*49+po] store is contiguous.
__global__ __launch_bounds__(512) void pool2_kernel(const float* __restrict__ data_t,
                                                    const float* __restrict__ rois,
                                                    const float* __restrict__ offs,
                                                    const float* __restrict__ mask,
                                                    float* __restrict__ out) {
    __shared__ float tile[FIN];       // 50,176 B
    __shared__ unsigned desc[784];
    __shared__ float2 dxy[784];
    __shared__ float scale[49];
    int n = blockIdx.x, tid = threadIdx.x;
    int b; float sw, sh, rw, rh;
    roi_geom(rois, n, b, sw, sh, rw, rh);
    float bw = rw / 7.0f, bh = rh / 7.0f;
    float subw = bw * 0.25f, subh = bh * 0.25f;
    if (tid < 49) scale[tid] = 0.f;
    __syncthreads();
    for (int idx = tid; idx < 784; idx += 512) {
        int po = idx >> 4, s = idx & 15;
        int ph = po / 7, pw = po - ph * 7;
        float ow = offs[(size_t)n * 98 + po];
        float oh = offs[(size_t)n * 98 + 49 + po];
        float w = (float)pw * bw + sw + ow * 0.1f * rw + (float)(s & 3) * subw;
        float h = (float)ph * bh + sh + oh * 0.1f * rh + (float)(s >> 2) * subh;
        float2 xy;
        unsigned d = sample_desc(w, h, xy);
        desc[idx] = d;
        dxy[idx] = xy;
        if ((int)d < 0) atomicAdd(&scale[po], 1.f);
    }
    __syncthreads();
    if (tid < 49) {
        float c = scale[tid];
        scale[tid] = c > 0.f ? mask[(size_t)n * 49 + tid] / c : 0.f;
    }
    __syncthreads();
    int wave = tid >> 6, lane = tid & 63, c4 = lane << 2;
    const float* dpb = data_t + (size_t)b * (HDIM * WDIM * CDIM) + c4;
    for (int po = wave; po < 49; po += 8) {
        float4 acc = make_float4(0.f, 0.f, 0.f, 0.f);
#pragma unroll 4
        for (int s = 0; s < 16; ++s) {
            unsigned d = desc[po * 16 + s];
            if ((int)d < 0) {
                float2 xy = dxy[po * 16 + s];
                int off = d & 0x3FFFFF;
                int xo = (d >> 21) & 0x100;
                int yo = (d >> 15) & 0x8000;
                const float* p = dpb + off;
                float4 v00 = *(const float4*)(p);
                float4 v01 = *(const float4*)(p + xo);
                float4 v10 = *(const float4*)(p + yo);
                float4 v11 = *(const float4*)(p + xo + yo);
                float ax = 1.f - xy.x, ay = 1.f - xy.y;
                float w00 = ax * ay, w01 = xy.x * ay, w10 = ax * xy.y, w11 = xy.x * xy.y;
                acc.x += w00 * v00.x + w01 * v01.x + w10 * v10.x + w11 * v11.x;
                acc.y += w00 * v00.y + w01 * v01.y + w10 * v10.y + w11 * v11.y;
                acc.z += w00 * v00.z + w01 * v01.z + w10 * v10.z + w11 * v11.z;
                acc.w += w00 * v00.w + w01 * v01.w + w10 * v10.w + w11 * v11.w;
            }
        }
        float sc = scale[po];
        // tile[(c)*49+po], XOR-swizzled to break the stride-196 bank pattern
        int a0 = c4 * 49 + po;
#pragma unroll
        for (int cc = 0; cc < 4; ++cc) {
            int a = a0 + cc * 49;
            tile[a ^ ((a >> 5) & 31)] = ((&acc.x)[cc]) * sc;
        }
    }
    __syncthreads();
    float* op = out + (size_t)n * FIN;
    for (int i = tid; i < FIN; i += 512) op[i] = tile[i ^ ((i >> 5) & 31)];
}

// MFMA bf16 GEMM: P[z] = A[M,K] @ Bt[N,K]^T  (fp32 partials, split-K).
__global__ __launch_bounds__(256) void gemm_mfma_kernel(
        const bf16r* __restrict__ A, int lda,
        const bf16r* __restrict__ Bt, int K,
        float* __restrict__ P, int Npad, int KS) {
    __shared__ bf16r As[128 * 32];
    __shared__ bf16r Bs[128 * 32];
    int tid = threadIdx.x;
    int wave = tid >> 6, lane = tid & 63;
    int m0 = blockIdx.y << 7, n0 = blockIdx.x << 7;
    int z = blockIdx.z;

    int srow = lane >> 2;
    int kchunk = ((lane & 3) ^ ((lane >> 3) & 3)) << 3;
    const bf16r* aG0 = A + (size_t)(m0 + wave * 32 + srow) * lda + kchunk;
    const bf16r* aG1 = A + (size_t)(m0 + wave * 32 + 16 + srow) * lda + kchunk;
    const bf16r* bG0 = Bt + (size_t)(n0 + wave * 32 + srow) * K + kchunk;
    const bf16r* bG1 = Bt + (size_t)(n0 + wave * 32 + 16 + srow) * K + kchunk;
    bf16r* aL0 = As + wave * 1024;
    bf16r* aL1 = As + wave * 1024 + 512;
    bf16r* bL0 = Bs + wave * 1024;
    bf16r* bL1 = Bs + wave * 1024 + 512;

    int l15 = lane & 15, quad = lane >> 4;
    int wr = wave >> 1, wc = wave & 1;
    int psw = (quad ^ ((l15 >> 1) & 3)) << 3;
    int aoff[4], boff[4];
#pragma unroll
    for (int t = 0; t < 4; ++t) {
        aoff[t] = ((wr * 64 + t * 16 + l15) * 32 + psw) * 2;
        boff[t] = ((wc * 64 + t * 16 + l15) * 32 + psw) * 2;
    }

    f32x4 acc[4][4];
#pragma unroll
    for (int i = 0; i < 4; ++i)
#pragma unroll
        for (int j = 0; j < 4; ++j) acc[i][j] = (f32x4){0.f, 0.f, 0.f, 0.f};

    int iters = K >> 5;
    int i0 = (int)((long)iters * z / KS);
    int i1 = (int)((long)iters * (z + 1) / KS);

    {
        size_t k0 = (size_t)i0 << 5;
        async16(aG0 + k0, aL0); async16(aG1 + k0, aL1);
        async16(bG0 + k0, bL0); async16(bG1 + k0, bL1);
    }
    for (int it = i0; it < i1; ++it) {
        __syncthreads();
        bf16x8 af[4], bfv[4];
#pragma unroll
        for (int t = 0; t < 4; ++t) af[t] = *(const bf16x8*)((const char*)As + aoff[t]);
#pragma unroll
        for (int t = 0; t < 4; ++t) bfv[t] = *(const bf16x8*)((const char*)Bs + boff[t]);
        __syncthreads();
        if (it + 1 < i1) {
            size_t k0 = (size_t)(it + 1) << 5;
            async16(aG0 + k0, aL0); async16(aG1 + k0, aL1);
            async16(bG0 + k0, bL0); async16(bG1 + k0, bL1);
        }
#pragma unroll
        for (int i = 0; i < 4; ++i)
#pragma unroll
            for (int j = 0; j < 4; ++j)
                acc[i][j] = __builtin_amdgcn_mfma_f32_16x16x32_bf16(af[i], bfv[j], acc[i][j], 0, 0, 0);
    }

    float* Pp = P + (size_t)z * MPAD * Npad;
#pragma unroll
    for (int i = 0; i < 4; ++i) {
        int row = m0 + wr * 64 + i * 16 + quad * 4;
#pragma unroll
        for (int j = 0; j < 4; ++j) {
            int col = n0 + wc * 64 + j * 16 + l15;
            float* o = Pp + (size_t)row * Npad + col;
#pragma unroll
            for (int r = 0; r < 4; ++r) o[(size_t)r * Npad] = acc[i][j][r];
        }
    }
}

// sum split-K partials + bias + activation + dtype convert
__global__ __launch_bounds__(256) void reduce_kernel(
        const float* __restrict__ P, int shift, int KS,
        const float* __restrict__ bias0, const float* __restrict__ bias1, int bsplit,
        void* __restrict__ Out, int ldo, int M, int Nreal, int outmode) {
    int idx = blockIdx.x * 256 + threadIdx.x;
    int Npad = 1 << shift;
    int row = idx >> shift, col = idx & (Npad - 1);
    float s = 0.f;
    size_t plane = (size_t)MPAD << shift;
    for (int zz = 0; zz < KS; ++zz) s += P[(size_t)zz * plane + idx];
    if (row < M && col < Nreal) {
        float b = (col < bsplit) ? bias0[col] : bias1[col - bsplit];
        float v = s + b;
        if (outmode == 0) {
            v = fmaxf(v, 0.f);
            ((bf16r*)Out)[(size_t)row * ldo + col] = f2bf(v);
        } else {
            if (outmode == 2) v = 1.f / (1.f + expf(-v));
            ((float*)Out)[(size_t)row * ldo + col] = v;
        }
    }
}

extern "C" void kernel_launch(void* const* d_in, const int* in_sizes, int n_in,
                              void* d_out, int out_size, void* d_ws, size_t ws_size,
                              hipStream_t stream) {
    const float* data = (const float*)d_in[0];
    const float* rois = (const float*)d_in[1];
    const float* w1   = (const float*)d_in[2];
    const float* b1   = (const float*)d_in[3];
    const float* w2   = (const float*)d_in[4];
    const float* b2   = (const float*)d_in[5];
    const float* w3   = (const float*)d_in[6];
    const float* b3   = (const float*)d_in[7];
    const float* mw1  = (const float*)d_in[8];
    const float* mb1  = (const float*)d_in[9];
    const float* mw2  = (const float*)d_in[10];
    const float* mb2  = (const float*)d_in[11];
    float* out = (float*)d_out;

    char* w = (char*)d_ws;
    size_t off = 0;
    auto carve = [&](size_t bytes) {
        void* p = w + off;
        off += (bytes + 255) & ~(size_t)255;
        return p;
    };
    float* data_t = (float*)carve((size_t)BDIM * HDIM * WDIM * CDIM * 4);
    bf16r* xf     = (bf16r*)carve((size_t)MPAD * FIN * 2);
    bf16r* bt1    = (bf16r*)carve((size_t)MPAD * FIN * 2);
    bf16r* hm     = (bf16r*)carve((size_t)MPAD * 2048 * 2);
    bf16r* h2     = (bf16r*)carve((size_t)MPAD * 1024 * 2);
    bf16r* bt2    = (bf16r*)carve((size_t)1024 * 1024 * 2);
    bf16r* bt3    = (bf16r*)carve((size_t)128 * 1024 * 2);
    bf16r* bt4    = (bf16r*)carve((size_t)128 * 1024 * 2);
    float* offs   = (float*)carve((size_t)NROI * 98 * 4);
    float* maskb  = (float*)carve((size_t)NROI * 49 * 4);
    float* P      = (float*)carve((size_t)3 * MPAD * 2048 * 4);

    conv_kernel<<<dim3(392, 64), 256, 0, stream>>>(w1, mw1, 1024, 1024, 2048, FIN, 1, bt1);
    conv_kernel<<<dim3(32, 32), 256, 0, stream>>>(w2, w2, 1 << 30, 1024, 1024, 1024, 0, bt2);
    conv_kernel<<<dim3(32, 4), 256, 0, stream>>>(w3, w3, 1 << 30, 98, 98, 1024, 0, bt3);
    conv_kernel<<<dim3(32, 2), 256, 0, stream>>>(mw2, mw2, 1 << 30, 49, 49, 1024, 0, bt4);
    transpose_kernel<<<dim3(4, 8, 512), dim3(32, 8), 0, stream>>>(data, data_t);
    pool1_kernel<<<dim3(NROI), 512, 0, stream>>>(data_t, rois, xf);

    gemm_mfma_kernel<<<dim3(16, 16, 3), 256, 0, stream>>>(xf, FIN, bt1, FIN, P, 2048, 3);
    reduce_kernel<<<16384, 256, 0, stream>>>(P, 11, 3, b1, mb1, 1024, hm, 2048, NROI, 2048, 0);
    gemm_mfma_kernel<<<dim3(8, 16, 4), 256, 0, stream>>>(hm, 2048, bt2, 1024, P, 1024, 4);
    reduce_kernel<<<8192, 256, 0, stream>>>(P, 10, 4, b2, b2, 1 << 30, h2, 1024, NROI, 1024, 0);
    gemm_mfma_kernel<<<dim3(1, 16, 8), 256, 0, stream>>>(h2, 1024, bt3, 1024, P, 128, 8);
    reduce_kernel<<<1024, 256, 0, stream>>>(P, 7, 8, b3, b3, 1 << 30, offs, 98, NROI, 98, 1);
    gemm_mfma_kernel<<<dim3(1, 16, 8), 256, 0, stream>>>(hm + 1024, 2048, bt4, 1024, P, 128, 8);
    reduce_kernel<<<1024, 256, 0, stream>>>(P, 7, 8, mb2, mb2, 1 << 30, maskb, 49, NROI, 49, 2);

    pool2_kernel<<<dim3(NROI), 512, 0, stream>>>(data_t, rois, offs, maskb, out);
}